// Round 6
// baseline (964.549 us; speedup 1.0000x reference)
//
#include <hip/hip_runtime.h>
#include <hip/hip_bf16.h>

// RGAT encoder, round 6:
//  - bf16 MFMA GEMM with fused attention-logit epilogue (unchanged)
//  - CSR keyed by (node, relation); scatter ALSO accumulates per-(node,rel,head)
//    softmax denominators via atomicAdd (low contention, avg 5 edges/key)
//  - aggregate: block per node, full wave per edge (ushort4/lane), explicit
//    4-wide batched loads (4 independent csr->z chains in flight), relation
//    as unrolled compile-time constant, alpha = cee * inv_den (den precomputed)
//    -> single accumulator set, no branch, no shuffles, 4KB LDS combine.

#define RN 100000
#define RE 500000
#define RH 4
#define RIN 256
#define RR 3
#define RHF 256
#define NE3 (RR * RE)
#define N3  (RR * RN)

typedef __attribute__((ext_vector_type(8))) short short8;
typedef __attribute__((ext_vector_type(4))) float f32x4;

static __device__ __forceinline__ float b2f(unsigned short u) {
  return __uint_as_float(((unsigned int)u) << 16);
}
static __device__ __forceinline__ unsigned short f2b(float f) {
  unsigned int u = __float_as_uint(f);
  u += 0x7FFF + ((u >> 16) & 1);   // RNE
  return (unsigned short)(u >> 16);
}

// ---------------- conversions ----------------
__global__ __launch_bounds__(256) void rgat_convx(
    const float* __restrict__ x, unsigned short* __restrict__ xb) {
  const size_t i = ((size_t)blockIdx.x * 256 + threadIdx.x) * 4;
  if (i >= (size_t)RN * RIN) return;
  const float4 v = *(const float4*)(x + i);
  ushort4 o;
  o.x = f2b(v.x); o.y = f2b(v.y); o.z = f2b(v.z); o.w = f2b(v.w);
  *(ushort4*)(xb + i) = o;
}

// W[r][k][n] f32 -> Wbt[r][n][k] bf16
__global__ __launch_bounds__(256) void rgat_convw(
    const float* __restrict__ W, unsigned short* __restrict__ wbt) {
  const int o = blockIdx.x * 256 + threadIdx.x;
  if (o >= RR * RIN * RHF) return;
  const int r = o / (RIN * RHF);
  const int rem = o - r * (RIN * RHF);
  const int n = rem >> 8;
  const int k = rem & 255;
  wbt[o] = f2b(W[r * (RIN * RHF) + k * RHF + n]);
}

// ------- GEMM: zb[r] = xb @ Wbt[r]^T (bf16, f32 acc) + fused el/er ----------
__global__ __launch_bounds__(256) void rgat_gemm_bf16(
    const unsigned short* __restrict__ xb, const unsigned short* __restrict__ wbt,
    unsigned short* __restrict__ zb, const float* __restrict__ al,
    const float* __restrict__ ar, float* __restrict__ el,
    float* __restrict__ er) {
  __shared__ unsigned short As[128 * 32];
  __shared__ unsigned short Bs[128 * 32];
  const int tid = threadIdx.x;
  const int lane = tid & 63, wid = tid >> 6;
  const int wr = wid >> 1, wc = wid & 1;
  const int m0 = blockIdx.x * 128;
  const int n0 = blockIdx.y * 128;
  const int r  = blockIdx.z;

  f32x4 acc[4][4] = {};
  const unsigned short* Bbase = wbt + (size_t)r * (RIN * RHF);

  for (int k0 = 0; k0 < RIN; k0 += 32) {
#pragma unroll
    for (int i = 0; i < 2; ++i) {
      const int c = wid * 128 + i * 64 + lane;
      const int row = c >> 2, c4 = c & 3;
      const unsigned short* ga = xb + (size_t)(m0 + row) * RIN + k0 + c4 * 8;
      __builtin_amdgcn_global_load_lds(
          (const __attribute__((address_space(1))) void*)ga,
          (__attribute__((address_space(3))) void*)(As + (wid * 128 + i * 64) * 8),
          16, 0, 0);
      const unsigned short* gb = Bbase + (size_t)(n0 + row) * RIN + k0 + c4 * 8;
      __builtin_amdgcn_global_load_lds(
          (const __attribute__((address_space(1))) void*)gb,
          (__attribute__((address_space(3))) void*)(Bs + (wid * 128 + i * 64) * 8),
          16, 0, 0);
    }
    asm volatile("s_waitcnt vmcnt(0)" ::: "memory");
    __syncthreads();

    short8 af[4], bfr[4];
#pragma unroll
    for (int mi = 0; mi < 4; ++mi)
      af[mi] = *(const short8*)(As + ((wr * 64 + mi * 16 + (lane & 15)) * 32 + (lane >> 4) * 8));
#pragma unroll
    for (int ni = 0; ni < 4; ++ni)
      bfr[ni] = *(const short8*)(Bs + ((wc * 64 + ni * 16 + (lane & 15)) * 32 + (lane >> 4) * 8));
#pragma unroll
    for (int mi = 0; mi < 4; ++mi)
#pragma unroll
      for (int ni = 0; ni < 4; ++ni)
        acc[mi][ni] = __builtin_amdgcn_mfma_f32_16x16x32_bf16(af[mi], bfr[ni], acc[mi][ni], 0, 0, 0);
    __syncthreads();
  }

  const int head = blockIdx.y * 2 + wc;
  float alv[4], arv[4];
#pragma unroll
  for (int ni = 0; ni < 4; ++ni) {
    alv[ni] = al[r * RHF + head * 64 + ni * 16 + (lane & 15)];
    arv[ni] = ar[r * RHF + head * 64 + ni * 16 + (lane & 15)];
  }

  const int mbase = m0 + wr * 64;
#pragma unroll
  for (int mi = 0; mi < 4; ++mi) {
#pragma unroll
    for (int q = 0; q < 4; ++q) {
      const int m = mbase + mi * 16 + (lane >> 4) * 4 + q;
      float pl = 0.f, pr = 0.f;
#pragma unroll
      for (int ni = 0; ni < 4; ++ni) {
        pl += acc[mi][ni][q] * alv[ni];
        pr += acc[mi][ni][q] * arv[ni];
      }
#pragma unroll
      for (int off = 1; off < 16; off <<= 1) {
        pl += __shfl_xor(pl, off);
        pr += __shfl_xor(pr, off);
      }
      if (m < RN) {
        if ((lane & 15) == 0) {
          el[(size_t)(r * (size_t)RN + m) * RH + head] = pl;
          er[(size_t)(r * (size_t)RN + m) * RH + head] = pr;
        }
        unsigned short* zrow = zb + (size_t)r * ((size_t)RN * RHF) + (size_t)m * RHF
                               + n0 + wc * 64 + (lane & 15);
#pragma unroll
        for (int ni = 0; ni < 4; ++ni) zrow[ni * 16] = f2b(acc[mi][ni][q]);
      }
    }
  }
}

// ---------------- CSR build keyed by (node, relation) ----------------
__global__ __launch_bounds__(256) void rgat_hist(
    const int* __restrict__ dst, int* __restrict__ deg2) {
  const int i = blockIdx.x * 256 + threadIdx.x;
  if (i >= NE3) return;
  const int r = i / RE;
  atomicAdd(&deg2[dst[i] * RR + r], 1);
}

__global__ __launch_bounds__(256) void rgat_scan1(
    const int* __restrict__ deg, int* __restrict__ offs, int* __restrict__ bsum) {
  __shared__ int sh[256];
  const int tid = threadIdx.x;
  const int base = blockIdx.x * 1024 + tid * 4;
  int v[4]; int s = 0;
#pragma unroll
  for (int j = 0; j < 4; ++j) {
    v[j] = (base + j < N3) ? deg[base + j] : 0;
    s += v[j];
  }
  sh[tid] = s;
  __syncthreads();
  for (int off = 1; off < 256; off <<= 1) {
    int t = (tid >= off) ? sh[tid - off] : 0;
    __syncthreads();
    sh[tid] += t;
    __syncthreads();
  }
  int run = sh[tid] - s;
  if (tid == 255) bsum[blockIdx.x] = sh[255];
#pragma unroll
  for (int j = 0; j < 4; ++j) {
    if (base + j < N3) offs[base + j] = run;
    run += v[j];
  }
}

__global__ __launch_bounds__(512) void rgat_scan2(int* __restrict__ bsum, int nb) {
  __shared__ int sh[512];
  const int tid = threadIdx.x;
  const int v = (tid < nb) ? bsum[tid] : 0;
  sh[tid] = v;
  __syncthreads();
  for (int off = 1; off < 512; off <<= 1) {
    int t = (tid >= off) ? sh[tid - off] : 0;
    __syncthreads();
    sh[tid] += t;
    __syncthreads();
  }
  if (tid < nb) bsum[tid] = sh[tid] - v;
}

__global__ __launch_bounds__(256) void rgat_scan3(
    int* __restrict__ offs, const int* __restrict__ bsum) {
  const int base = blockIdx.x * 1024 + threadIdx.x * 4;
  const int b = bsum[blockIdx.x];
#pragma unroll
  for (int j = 0; j < 4; ++j)
    if (base + j < N3) offs[base + j] += b;
}

// scatter: csrc[pos]=src, cee[pos]=exp numerators, den[key][h] += numerators
__global__ __launch_bounds__(256) void rgat_scatter(
    const int* __restrict__ src, const int* __restrict__ dst,
    const float* __restrict__ el, const float* __restrict__ er,
    int* __restrict__ offs2, int* __restrict__ csrc,
    float4* __restrict__ cee, float* __restrict__ den) {
  const int i = blockIdx.x * 256 + threadIdx.x;
  if (i >= NE3) return;
  const int r = i / RE;
  const int s = src[i];
  const int d = dst[i];
  const int key = d * RR + r;
  const int pos = atomicAdd(&offs2[key], 1);
  const float4 elv = *(const float4*)(el + (size_t)(r * (size_t)RN + s) * RH);
  const float4 erv = *(const float4*)(er + (size_t)(r * (size_t)RN + d) * RH);
  float e0 = elv.x + erv.x, e1 = elv.y + erv.y, e2 = elv.z + erv.z, e3 = elv.w + erv.w;
  e0 = e0 > 0.f ? e0 : 0.2f * e0;
  e1 = e1 > 0.f ? e1 : 0.2f * e1;
  e2 = e2 > 0.f ? e2 : 0.2f * e2;
  e3 = e3 > 0.f ? e3 : 0.2f * e3;
  const float p0 = __expf(e0), p1 = __expf(e1), p2 = __expf(e2), p3 = __expf(e3);
  csrc[pos] = s;
  cee[pos] = make_float4(p0, p1, p2, p3);
  float* dn = den + (size_t)key * RH;
  atomicAdd(&dn[0], p0);
  atomicAdd(&dn[1], p1);
  atomicAdd(&dn[2], p2);
  atomicAdd(&dn[3], p3);
}

// -------- aggregate: block per node; wave per edge; 4-wide batched; no branch
__global__ __launch_bounds__(256) void rgat_aggregate(
    const unsigned short* __restrict__ zb, const int* __restrict__ csrc,
    const float* __restrict__ ceef, const int* __restrict__ deg2,
    const int* __restrict__ offs2, const float* __restrict__ den,
    const float* __restrict__ bias, float* __restrict__ out) {
  __shared__ float shn[4][RHF];   // 4 KB
  const int n = blockIdx.x;
  const int tid = threadIdx.x;
  const int wid = tid >> 6, lane = tid & 63;
  const int h = lane >> 4;
  const int c = lane * 4;

  float a0 = 0.f, a1 = 0.f, a2 = 0.f, a3 = 0.f;

#pragma unroll
  for (int r = 0; r < RR; ++r) {
    const int key = n * RR + r;
    const int dr = deg2[key];
    const int start = offs2[key] - dr;   // offs2 is segment END after scatter
    const float dn = den[(size_t)key * RH + h];
    const float inv = (dn > 0.f) ? 1.f / dn : 0.f;
    const unsigned short* zB = zb + (size_t)r * ((size_t)RN * RHF) + c;
    for (int base = wid; base < dr; base += 16) {
      int ss[4];
      float aa[4];
      ushort4 zv[4];
#pragma unroll
      for (int j = 0; j < 4; ++j) {
        const int t = base + j * 4;       // wave-uniform
        if (t < dr) {
          const int p = start + t;
          ss[j] = csrc[p];
          aa[j] = ceef[p * 4 + h];
        } else {
          ss[j] = -1;
        }
      }
#pragma unroll
      for (int j = 0; j < 4; ++j)
        if (ss[j] >= 0) zv[j] = *(const ushort4*)(zB + (size_t)ss[j] * RHF);
#pragma unroll
      for (int j = 0; j < 4; ++j) {
        if (ss[j] < 0) continue;          // wave-uniform scalar branch
        const float a = aa[j] * inv;
        a0 += a * b2f(zv[j].x);
        a1 += a * b2f(zv[j].y);
        a2 += a * b2f(zv[j].z);
        a3 += a * b2f(zv[j].w);
      }
    }
  }

  *(float4*)&shn[wid][c] = make_float4(a0, a1, a2, a3);
  __syncthreads();

  const int col = tid;
  float v = shn[0][col] + shn[1][col] + shn[2][col] + shn[3][col]
          + bias[col] + bias[RHF + col] + bias[2 * RHF + col];
  v = v > 0.f ? v : (__expf(v) - 1.f);
  out[(size_t)n * RHF + col] = v;
}

extern "C" void kernel_launch(void* const* d_in, const int* in_sizes, int n_in,
                              void* d_out, int out_size, void* d_ws, size_t ws_size,
                              hipStream_t stream) {
  const float* x    = (const float*)d_in[0];
  const float* W    = (const float*)d_in[1];
  const float* al   = (const float*)d_in[2];
  const float* ar   = (const float*)d_in[3];
  const float* bias = (const float*)d_in[4];
  const int*   src  = (const int*)d_in[5];
  const int*   dst  = (const int*)d_in[6];
  float* out = (float*)d_out;

  // workspace layout (bytes), total ~253 MB
  char* p = (char*)d_ws;
  unsigned short* xb  = (unsigned short*)p; p += (size_t)RN * RIN * 2;        // 51.2 MB
  unsigned short* wbt = (unsigned short*)p; p += (size_t)RR * RIN * RHF * 2;  // 0.39 MB
  unsigned short* zb  = (unsigned short*)p; p += (size_t)RR * RN * RHF * 2;   // 153.6 MB
  float* el    = (float*)p;  p += (size_t)RR * RN * RH * 4;                   // 4.8 MB
  float* er    = (float*)p;  p += (size_t)RR * RN * RH * 4;                   // 4.8 MB
  int* deg2    = (int*)p;    p += (size_t)N3 * 4;                             // 1.2 MB
  float* den   = (float*)p;  p += (size_t)N3 * RH * 4;                        // 4.8 MB (contiguous with deg2 for one memset)
  int* offs2   = (int*)p;    p += (size_t)N3 * 4;                             // 1.2 MB
  int* csrc    = (int*)p;    p += (size_t)NE3 * 4;                            // 6.0 MB
  float4* cee  = (float4*)p; p += (size_t)NE3 * 16;                           // 24.0 MB
  int* bsum    = (int*)p;    p += 2048;

  const int NB1 = (N3 + 1023) / 1024;   // 293

  // zero deg2 + den in one shot (contiguous)
  hipMemsetAsync(deg2, 0, (size_t)N3 * 4 + (size_t)N3 * RH * 4, stream);

  rgat_convx<<<(RN * RIN / 4 + 255) / 256, 256, 0, stream>>>(x, xb);
  rgat_convw<<<(RR * RIN * RHF + 255) / 256, 256, 0, stream>>>(W, wbt);

  rgat_hist<<<(NE3 + 255) / 256, 256, 0, stream>>>(dst, deg2);
  rgat_scan1<<<NB1, 256, 0, stream>>>(deg2, offs2, bsum);
  rgat_scan2<<<1, 512, 0, stream>>>(bsum, NB1);
  rgat_scan3<<<NB1, 256, 0, stream>>>(offs2, bsum);

  rgat_gemm_bf16<<<dim3((RN + 127) / 128, RHF / 128, RR), 256, 0, stream>>>(
      xb, wbt, zb, al, ar, el, er);

  rgat_scatter<<<(NE3 + 255) / 256, 256, 0, stream>>>(src, dst, el, er, offs2,
                                                      csrc, cee, den);

  rgat_aggregate<<<RN, 256, 0, stream>>>(zb, csrc, (const float*)cee, deg2,
                                         offs2, den, bias, out);
}

// Round 8
// 740.820 us; speedup vs baseline: 1.3020x; 1.3020x over previous
//
#include <hip/hip_runtime.h>
#include <hip/hip_bf16.h>

// RGAT encoder, round 7 (resubmit — r7 bench hit GPUAcquisitionTimeout):
//  - bf16 MFMA GEMM with fused attention-logit epilogue (unchanged)
//  - CSR keyed by (node, relation); scatter writes {csrc, cee} only (NO den
//    atomics — r6's 365us regression). Denominators via rgat_den: one thread
//    per key sums its contiguous cee segment, stores 1/den.
//  - aggregate: block per node; HALF-WAVE per edge (short8 = 16B/lane) with
//    explicit 4-wide batching -> 8 edges in flight per wave; relation as
//    unrolled constant; alpha = cee * inv_den; branch-free tail (ss=0,a=0);
//    single shfl_xor(32) fold at end + 4KB LDS combine.

#define RN 100000
#define RE 500000
#define RH 4
#define RIN 256
#define RR 3
#define RHF 256
#define NE3 (RR * RE)
#define N3  (RR * RN)

typedef __attribute__((ext_vector_type(8))) short short8;
typedef __attribute__((ext_vector_type(4))) float f32x4;

static __device__ __forceinline__ float b2f(unsigned short u) {
  return __uint_as_float(((unsigned int)u) << 16);
}
static __device__ __forceinline__ unsigned short f2b(float f) {
  unsigned int u = __float_as_uint(f);
  u += 0x7FFF + ((u >> 16) & 1);   // RNE
  return (unsigned short)(u >> 16);
}

// ---------------- conversions ----------------
__global__ __launch_bounds__(256) void rgat_convx(
    const float* __restrict__ x, unsigned short* __restrict__ xb) {
  const size_t i = ((size_t)blockIdx.x * 256 + threadIdx.x) * 4;
  if (i >= (size_t)RN * RIN) return;
  const float4 v = *(const float4*)(x + i);
  ushort4 o;
  o.x = f2b(v.x); o.y = f2b(v.y); o.z = f2b(v.z); o.w = f2b(v.w);
  *(ushort4*)(xb + i) = o;
}

// W[r][k][n] f32 -> Wbt[r][n][k] bf16
__global__ __launch_bounds__(256) void rgat_convw(
    const float* __restrict__ W, unsigned short* __restrict__ wbt) {
  const int o = blockIdx.x * 256 + threadIdx.x;
  if (o >= RR * RIN * RHF) return;
  const int r = o / (RIN * RHF);
  const int rem = o - r * (RIN * RHF);
  const int n = rem >> 8;
  const int k = rem & 255;
  wbt[o] = f2b(W[r * (RIN * RHF) + k * RHF + n]);
}

// ------- GEMM: zb[r] = xb @ Wbt[r]^T (bf16, f32 acc) + fused el/er ----------
__global__ __launch_bounds__(256) void rgat_gemm_bf16(
    const unsigned short* __restrict__ xb, const unsigned short* __restrict__ wbt,
    unsigned short* __restrict__ zb, const float* __restrict__ al,
    const float* __restrict__ ar, float* __restrict__ el,
    float* __restrict__ er) {
  __shared__ unsigned short As[128 * 32];
  __shared__ unsigned short Bs[128 * 32];
  const int tid = threadIdx.x;
  const int lane = tid & 63, wid = tid >> 6;
  const int wr = wid >> 1, wc = wid & 1;
  const int m0 = blockIdx.x * 128;
  const int n0 = blockIdx.y * 128;
  const int r  = blockIdx.z;

  f32x4 acc[4][4] = {};
  const unsigned short* Bbase = wbt + (size_t)r * (RIN * RHF);

  for (int k0 = 0; k0 < RIN; k0 += 32) {
#pragma unroll
    for (int i = 0; i < 2; ++i) {
      const int c = wid * 128 + i * 64 + lane;
      const int row = c >> 2, c4 = c & 3;
      const unsigned short* ga = xb + (size_t)(m0 + row) * RIN + k0 + c4 * 8;
      __builtin_amdgcn_global_load_lds(
          (const __attribute__((address_space(1))) void*)ga,
          (__attribute__((address_space(3))) void*)(As + (wid * 128 + i * 64) * 8),
          16, 0, 0);
      const unsigned short* gb = Bbase + (size_t)(n0 + row) * RIN + k0 + c4 * 8;
      __builtin_amdgcn_global_load_lds(
          (const __attribute__((address_space(1))) void*)gb,
          (__attribute__((address_space(3))) void*)(Bs + (wid * 128 + i * 64) * 8),
          16, 0, 0);
    }
    asm volatile("s_waitcnt vmcnt(0)" ::: "memory");
    __syncthreads();

    short8 af[4], bfr[4];
#pragma unroll
    for (int mi = 0; mi < 4; ++mi)
      af[mi] = *(const short8*)(As + ((wr * 64 + mi * 16 + (lane & 15)) * 32 + (lane >> 4) * 8));
#pragma unroll
    for (int ni = 0; ni < 4; ++ni)
      bfr[ni] = *(const short8*)(Bs + ((wc * 64 + ni * 16 + (lane & 15)) * 32 + (lane >> 4) * 8));
#pragma unroll
    for (int mi = 0; mi < 4; ++mi)
#pragma unroll
      for (int ni = 0; ni < 4; ++ni)
        acc[mi][ni] = __builtin_amdgcn_mfma_f32_16x16x32_bf16(af[mi], bfr[ni], acc[mi][ni], 0, 0, 0);
    __syncthreads();
  }

  const int head = blockIdx.y * 2 + wc;
  float alv[4], arv[4];
#pragma unroll
  for (int ni = 0; ni < 4; ++ni) {
    alv[ni] = al[r * RHF + head * 64 + ni * 16 + (lane & 15)];
    arv[ni] = ar[r * RHF + head * 64 + ni * 16 + (lane & 15)];
  }

  const int mbase = m0 + wr * 64;
#pragma unroll
  for (int mi = 0; mi < 4; ++mi) {
#pragma unroll
    for (int q = 0; q < 4; ++q) {
      const int m = mbase + mi * 16 + (lane >> 4) * 4 + q;
      float pl = 0.f, pr = 0.f;
#pragma unroll
      for (int ni = 0; ni < 4; ++ni) {
        pl += acc[mi][ni][q] * alv[ni];
        pr += acc[mi][ni][q] * arv[ni];
      }
#pragma unroll
      for (int off = 1; off < 16; off <<= 1) {
        pl += __shfl_xor(pl, off);
        pr += __shfl_xor(pr, off);
      }
      if (m < RN) {
        if ((lane & 15) == 0) {
          el[(size_t)(r * (size_t)RN + m) * RH + head] = pl;
          er[(size_t)(r * (size_t)RN + m) * RH + head] = pr;
        }
        unsigned short* zrow = zb + (size_t)r * ((size_t)RN * RHF) + (size_t)m * RHF
                               + n0 + wc * 64 + (lane & 15);
#pragma unroll
        for (int ni = 0; ni < 4; ++ni) zrow[ni * 16] = f2b(acc[mi][ni][q]);
      }
    }
  }
}

// ---------------- CSR build keyed by (node, relation) ----------------
__global__ __launch_bounds__(256) void rgat_hist(
    const int* __restrict__ dst, int* __restrict__ deg2) {
  const int i = blockIdx.x * 256 + threadIdx.x;
  if (i >= NE3) return;
  const int r = i / RE;
  atomicAdd(&deg2[dst[i] * RR + r], 1);
}

__global__ __launch_bounds__(256) void rgat_scan1(
    const int* __restrict__ deg, int* __restrict__ offs, int* __restrict__ bsum) {
  __shared__ int sh[256];
  const int tid = threadIdx.x;
  const int base = blockIdx.x * 1024 + tid * 4;
  int v[4]; int s = 0;
#pragma unroll
  for (int j = 0; j < 4; ++j) {
    v[j] = (base + j < N3) ? deg[base + j] : 0;
    s += v[j];
  }
  sh[tid] = s;
  __syncthreads();
  for (int off = 1; off < 256; off <<= 1) {
    int t = (tid >= off) ? sh[tid - off] : 0;
    __syncthreads();
    sh[tid] += t;
    __syncthreads();
  }
  int run = sh[tid] - s;
  if (tid == 255) bsum[blockIdx.x] = sh[255];
#pragma unroll
  for (int j = 0; j < 4; ++j) {
    if (base + j < N3) offs[base + j] = run;
    run += v[j];
  }
}

__global__ __launch_bounds__(512) void rgat_scan2(int* __restrict__ bsum, int nb) {
  __shared__ int sh[512];
  const int tid = threadIdx.x;
  const int v = (tid < nb) ? bsum[tid] : 0;
  sh[tid] = v;
  __syncthreads();
  for (int off = 1; off < 512; off <<= 1) {
    int t = (tid >= off) ? sh[tid - off] : 0;
    __syncthreads();
    sh[tid] += t;
    __syncthreads();
  }
  if (tid < nb) bsum[tid] = sh[tid] - v;
}

__global__ __launch_bounds__(256) void rgat_scan3(
    int* __restrict__ offs, const int* __restrict__ bsum) {
  const int base = blockIdx.x * 1024 + threadIdx.x * 4;
  const int b = bsum[blockIdx.x];
#pragma unroll
  for (int j = 0; j < 4; ++j)
    if (base + j < N3) offs[base + j] += b;
}

// scatter: csrc[pos]=src, cee[pos]=exp numerators (NO den atomics)
__global__ __launch_bounds__(256) void rgat_scatter(
    const int* __restrict__ src, const int* __restrict__ dst,
    const float* __restrict__ el, const float* __restrict__ er,
    int* __restrict__ offs2, int* __restrict__ csrc,
    float4* __restrict__ cee) {
  const int i = blockIdx.x * 256 + threadIdx.x;
  if (i >= NE3) return;
  const int r = i / RE;
  const int s = src[i];
  const int d = dst[i];
  const int pos = atomicAdd(&offs2[d * RR + r], 1);
  const float4 elv = *(const float4*)(el + (size_t)(r * (size_t)RN + s) * RH);
  const float4 erv = *(const float4*)(er + (size_t)(r * (size_t)RN + d) * RH);
  float e0 = elv.x + erv.x, e1 = elv.y + erv.y, e2 = elv.z + erv.z, e3 = elv.w + erv.w;
  e0 = e0 > 0.f ? e0 : 0.2f * e0;
  e1 = e1 > 0.f ? e1 : 0.2f * e1;
  e2 = e2 > 0.f ? e2 : 0.2f * e2;
  e3 = e3 > 0.f ? e3 : 0.2f * e3;
  csrc[pos] = s;
  cee[pos] = make_float4(__expf(e0), __expf(e1), __expf(e2), __expf(e3));
}

// den: one thread per (node,rel) key; sum contiguous cee segment; store 1/den
__global__ __launch_bounds__(256) void rgat_den(
    const float4* __restrict__ cee, const int* __restrict__ deg2,
    const int* __restrict__ offs2, float* __restrict__ invd) {
  const int key = blockIdx.x * 256 + threadIdx.x;
  if (key >= N3) return;
  const int d = deg2[key];
  const int end = offs2[key];        // segment END after scatter
  float s0 = 0.f, s1 = 0.f, s2 = 0.f, s3 = 0.f;
  for (int p = end - d; p < end; ++p) {
    const float4 v = cee[p];
    s0 += v.x; s1 += v.y; s2 += v.z; s3 += v.w;
  }
  float4 o;
  o.x = s0 > 0.f ? 1.f / s0 : 0.f;
  o.y = s1 > 0.f ? 1.f / s1 : 0.f;
  o.z = s2 > 0.f ? 1.f / s2 : 0.f;
  o.w = s3 > 0.f ? 1.f / s3 : 0.f;
  *(float4*)(invd + (size_t)key * RH) = o;
}

// -------- aggregate: block per node; half-wave per edge; 4-wide batched ------
__global__ __launch_bounds__(256) void rgat_aggregate(
    const unsigned short* __restrict__ zb, const int* __restrict__ csrc,
    const float* __restrict__ ceef, const int* __restrict__ deg2,
    const int* __restrict__ offs2, const float* __restrict__ invd,
    const float* __restrict__ bias, float* __restrict__ out) {
  __shared__ float shn[4][RHF];   // 4 KB
  const int n = blockIdx.x;
  const int tid = threadIdx.x;
  const int wid = tid >> 6, lane = tid & 63;
  const int hw = lane >> 5;           // half-wave 0/1: even/odd edge
  const int sub = lane & 31;
  const int h = sub >> 3;             // head of my 8 columns
  const int c = sub * 8;              // my 8 columns

  float acc[8] = {};

#pragma unroll
  for (int r = 0; r < RR; ++r) {
    const int key = n * RR + r;
    const int dr = deg2[key];
    const int start = offs2[key] - dr;
    const float inv = invd[(size_t)key * RH + h];
    const unsigned short* zB = zb + (size_t)r * ((size_t)RN * RHF) + c;
    for (int base = wid * 8; base < dr; base += 32) {
      int ss[4]; float aa[4];
#pragma unroll
      for (int j = 0; j < 4; ++j) {
        const int t = base + j * 2 + hw;
        if (t < dr) {
          const int p = start + t;
          ss[j] = csrc[p];
          aa[j] = ceef[p * 4 + h];
        } else {
          ss[j] = 0;        // safe row, zero weight (branch-free tail)
          aa[j] = 0.f;
        }
      }
      short8 zv[4];
#pragma unroll
      for (int j = 0; j < 4; ++j)
        zv[j] = *(const short8*)(zB + (size_t)ss[j] * RHF);
#pragma unroll
      for (int j = 0; j < 4; ++j) {
        const float a = aa[j] * inv;
#pragma unroll
        for (int k = 0; k < 8; ++k)
          acc[k] += a * b2f((unsigned short)zv[j][k]);
      }
    }
  }

  // fold odd/even halves
#pragma unroll
  for (int k = 0; k < 8; ++k) acc[k] += __shfl_xor(acc[k], 32);

  if (lane < 32) {
    *(float4*)&shn[wid][c]     = make_float4(acc[0], acc[1], acc[2], acc[3]);
    *(float4*)&shn[wid][c + 4] = make_float4(acc[4], acc[5], acc[6], acc[7]);
  }
  __syncthreads();

  const int col = tid;
  float v = shn[0][col] + shn[1][col] + shn[2][col] + shn[3][col]
          + bias[col] + bias[RHF + col] + bias[2 * RHF + col];
  v = v > 0.f ? v : (__expf(v) - 1.f);
  out[(size_t)n * RHF + col] = v;
}

extern "C" void kernel_launch(void* const* d_in, const int* in_sizes, int n_in,
                              void* d_out, int out_size, void* d_ws, size_t ws_size,
                              hipStream_t stream) {
  const float* x    = (const float*)d_in[0];
  const float* W    = (const float*)d_in[1];
  const float* al   = (const float*)d_in[2];
  const float* ar   = (const float*)d_in[3];
  const float* bias = (const float*)d_in[4];
  const int*   src  = (const int*)d_in[5];
  const int*   dst  = (const int*)d_in[6];
  float* out = (float*)d_out;

  // workspace layout (bytes), total ~253 MB
  char* p = (char*)d_ws;
  unsigned short* xb  = (unsigned short*)p; p += (size_t)RN * RIN * 2;        // 51.2 MB
  unsigned short* wbt = (unsigned short*)p; p += (size_t)RR * RIN * RHF * 2;  // 0.39 MB
  unsigned short* zb  = (unsigned short*)p; p += (size_t)RR * RN * RHF * 2;   // 153.6 MB
  float* el    = (float*)p;  p += (size_t)RR * RN * RH * 4;                   // 4.8 MB
  float* er    = (float*)p;  p += (size_t)RR * RN * RH * 4;                   // 4.8 MB
  int* deg2    = (int*)p;    p += (size_t)N3 * 4;                             // 1.2 MB
  float* invd  = (float*)p;  p += (size_t)N3 * RH * 4;                        // 4.8 MB
  int* offs2   = (int*)p;    p += (size_t)N3 * 4;                             // 1.2 MB
  int* csrc    = (int*)p;    p += (size_t)NE3 * 4;                            // 6.0 MB
  float4* cee  = (float4*)p; p += (size_t)NE3 * 16;                           // 24.0 MB
  int* bsum    = (int*)p;    p += 2048;

  const int NB1 = (N3 + 1023) / 1024;   // 293

  hipMemsetAsync(deg2, 0, (size_t)N3 * 4, stream);

  rgat_convx<<<(RN * RIN / 4 + 255) / 256, 256, 0, stream>>>(x, xb);
  rgat_convw<<<(RR * RIN * RHF + 255) / 256, 256, 0, stream>>>(W, wbt);

  rgat_hist<<<(NE3 + 255) / 256, 256, 0, stream>>>(dst, deg2);
  rgat_scan1<<<NB1, 256, 0, stream>>>(deg2, offs2, bsum);
  rgat_scan2<<<1, 512, 0, stream>>>(bsum, NB1);
  rgat_scan3<<<NB1, 256, 0, stream>>>(offs2, bsum);

  rgat_gemm_bf16<<<dim3((RN + 127) / 128, RHF / 128, RR), 256, 0, stream>>>(
      xb, wbt, zb, al, ar, el, er);

  rgat_scatter<<<(NE3 + 255) / 256, 256, 0, stream>>>(src, dst, el, er, offs2,
                                                      csrc, cee);

  rgat_den<<<(N3 + 255) / 256, 256, 0, stream>>>(cee, deg2, offs2, invd);

  rgat_aggregate<<<RN, 256, 0, stream>>>(zb, csrc, (const float*)cee, deg2,
                                         offs2, invd, bias, out);
}

// Round 9
// 619.163 us; speedup vs baseline: 1.5578x; 1.1965x over previous
//
#include <hip/hip_runtime.h>
#include <hip/hip_bf16.h>

// RGAT encoder, round 9:
//  - bf16 MFMA GEMM with fused attention-logit epilogue (unchanged)
//  - CSR keyed by (node, relation); scatter stores czoff = r*RN+src and raw
//    exp numerators cee. rgat_norm normalizes cee -> alpha IN PLACE (one
//    thread per key over its contiguous segment).
//  - aggregate: merged per-node segment (3 contiguous key segments);
//    HALF-WAVE per edge (short8 = 16B/lane = full 512B z row); 8 half-waves
//    per block at stride-1 granularity, j=2 batch -> 16 edges in flight;
//    inner loop has NO relation logic, NO den: acc += alpha[p] * z[czoff[p]].
//    r8 lesson: distribution granularity (8/wave) >> deg (~5) serialized
//    everything onto wave 0; granularity is now 1 edge per half-wave.

#define RN 100000
#define RE 500000
#define RH 4
#define RIN 256
#define RR 3
#define RHF 256
#define NE3 (RR * RE)
#define N3  (RR * RN)

typedef __attribute__((ext_vector_type(8))) short short8;
typedef __attribute__((ext_vector_type(4))) float f32x4;

static __device__ __forceinline__ float b2f(unsigned short u) {
  return __uint_as_float(((unsigned int)u) << 16);
}
static __device__ __forceinline__ unsigned short f2b(float f) {
  unsigned int u = __float_as_uint(f);
  u += 0x7FFF + ((u >> 16) & 1);   // RNE
  return (unsigned short)(u >> 16);
}

// ---------------- conversions ----------------
__global__ __launch_bounds__(256) void rgat_convx(
    const float* __restrict__ x, unsigned short* __restrict__ xb) {
  const size_t i = ((size_t)blockIdx.x * 256 + threadIdx.x) * 4;
  if (i >= (size_t)RN * RIN) return;
  const float4 v = *(const float4*)(x + i);
  ushort4 o;
  o.x = f2b(v.x); o.y = f2b(v.y); o.z = f2b(v.z); o.w = f2b(v.w);
  *(ushort4*)(xb + i) = o;
}

// W[r][k][n] f32 -> Wbt[r][n][k] bf16
__global__ __launch_bounds__(256) void rgat_convw(
    const float* __restrict__ W, unsigned short* __restrict__ wbt) {
  const int o = blockIdx.x * 256 + threadIdx.x;
  if (o >= RR * RIN * RHF) return;
  const int r = o / (RIN * RHF);
  const int rem = o - r * (RIN * RHF);
  const int n = rem >> 8;
  const int k = rem & 255;
  wbt[o] = f2b(W[r * (RIN * RHF) + k * RHF + n]);
}

// ------- GEMM: zb[r] = xb @ Wbt[r]^T (bf16, f32 acc) + fused el/er ----------
__global__ __launch_bounds__(256) void rgat_gemm_bf16(
    const unsigned short* __restrict__ xb, const unsigned short* __restrict__ wbt,
    unsigned short* __restrict__ zb, const float* __restrict__ al,
    const float* __restrict__ ar, float* __restrict__ el,
    float* __restrict__ er) {
  __shared__ unsigned short As[128 * 32];
  __shared__ unsigned short Bs[128 * 32];
  const int tid = threadIdx.x;
  const int lane = tid & 63, wid = tid >> 6;
  const int wr = wid >> 1, wc = wid & 1;
  const int m0 = blockIdx.x * 128;
  const int n0 = blockIdx.y * 128;
  const int r  = blockIdx.z;

  f32x4 acc[4][4] = {};
  const unsigned short* Bbase = wbt + (size_t)r * (RIN * RHF);

  for (int k0 = 0; k0 < RIN; k0 += 32) {
#pragma unroll
    for (int i = 0; i < 2; ++i) {
      const int c = wid * 128 + i * 64 + lane;
      const int row = c >> 2, c4 = c & 3;
      const unsigned short* ga = xb + (size_t)(m0 + row) * RIN + k0 + c4 * 8;
      __builtin_amdgcn_global_load_lds(
          (const __attribute__((address_space(1))) void*)ga,
          (__attribute__((address_space(3))) void*)(As + (wid * 128 + i * 64) * 8),
          16, 0, 0);
      const unsigned short* gb = Bbase + (size_t)(n0 + row) * RIN + k0 + c4 * 8;
      __builtin_amdgcn_global_load_lds(
          (const __attribute__((address_space(1))) void*)gb,
          (__attribute__((address_space(3))) void*)(Bs + (wid * 128 + i * 64) * 8),
          16, 0, 0);
    }
    asm volatile("s_waitcnt vmcnt(0)" ::: "memory");
    __syncthreads();

    short8 af[4], bfr[4];
#pragma unroll
    for (int mi = 0; mi < 4; ++mi)
      af[mi] = *(const short8*)(As + ((wr * 64 + mi * 16 + (lane & 15)) * 32 + (lane >> 4) * 8));
#pragma unroll
    for (int ni = 0; ni < 4; ++ni)
      bfr[ni] = *(const short8*)(Bs + ((wc * 64 + ni * 16 + (lane & 15)) * 32 + (lane >> 4) * 8));
#pragma unroll
    for (int mi = 0; mi < 4; ++mi)
#pragma unroll
      for (int ni = 0; ni < 4; ++ni)
        acc[mi][ni] = __builtin_amdgcn_mfma_f32_16x16x32_bf16(af[mi], bfr[ni], acc[mi][ni], 0, 0, 0);
    __syncthreads();
  }

  const int head = blockIdx.y * 2 + wc;
  float alv[4], arv[4];
#pragma unroll
  for (int ni = 0; ni < 4; ++ni) {
    alv[ni] = al[r * RHF + head * 64 + ni * 16 + (lane & 15)];
    arv[ni] = ar[r * RHF + head * 64 + ni * 16 + (lane & 15)];
  }

  const int mbase = m0 + wr * 64;
#pragma unroll
  for (int mi = 0; mi < 4; ++mi) {
#pragma unroll
    for (int q = 0; q < 4; ++q) {
      const int m = mbase + mi * 16 + (lane >> 4) * 4 + q;
      float pl = 0.f, pr = 0.f;
#pragma unroll
      for (int ni = 0; ni < 4; ++ni) {
        pl += acc[mi][ni][q] * alv[ni];
        pr += acc[mi][ni][q] * arv[ni];
      }
#pragma unroll
      for (int off = 1; off < 16; off <<= 1) {
        pl += __shfl_xor(pl, off);
        pr += __shfl_xor(pr, off);
      }
      if (m < RN) {
        if ((lane & 15) == 0) {
          el[(size_t)(r * (size_t)RN + m) * RH + head] = pl;
          er[(size_t)(r * (size_t)RN + m) * RH + head] = pr;
        }
        unsigned short* zrow = zb + (size_t)r * ((size_t)RN * RHF) + (size_t)m * RHF
                               + n0 + wc * 64 + (lane & 15);
#pragma unroll
        for (int ni = 0; ni < 4; ++ni) zrow[ni * 16] = f2b(acc[mi][ni][q]);
      }
    }
  }
}

// ---------------- CSR build keyed by (node, relation) ----------------
__global__ __launch_bounds__(256) void rgat_hist(
    const int* __restrict__ dst, int* __restrict__ deg2) {
  const int i = blockIdx.x * 256 + threadIdx.x;
  if (i >= NE3) return;
  const int r = i / RE;
  atomicAdd(&deg2[dst[i] * RR + r], 1);
}

__global__ __launch_bounds__(256) void rgat_scan1(
    const int* __restrict__ deg, int* __restrict__ offs, int* __restrict__ bsum) {
  __shared__ int sh[256];
  const int tid = threadIdx.x;
  const int base = blockIdx.x * 1024 + tid * 4;
  int v[4]; int s = 0;
#pragma unroll
  for (int j = 0; j < 4; ++j) {
    v[j] = (base + j < N3) ? deg[base + j] : 0;
    s += v[j];
  }
  sh[tid] = s;
  __syncthreads();
  for (int off = 1; off < 256; off <<= 1) {
    int t = (tid >= off) ? sh[tid - off] : 0;
    __syncthreads();
    sh[tid] += t;
    __syncthreads();
  }
  int run = sh[tid] - s;
  if (tid == 255) bsum[blockIdx.x] = sh[255];
#pragma unroll
  for (int j = 0; j < 4; ++j) {
    if (base + j < N3) offs[base + j] = run;
    run += v[j];
  }
}

__global__ __launch_bounds__(512) void rgat_scan2(int* __restrict__ bsum, int nb) {
  __shared__ int sh[512];
  const int tid = threadIdx.x;
  const int v = (tid < nb) ? bsum[tid] : 0;
  sh[tid] = v;
  __syncthreads();
  for (int off = 1; off < 512; off <<= 1) {
    int t = (tid >= off) ? sh[tid - off] : 0;
    __syncthreads();
    sh[tid] += t;
    __syncthreads();
  }
  if (tid < nb) bsum[tid] = sh[tid] - v;
}

__global__ __launch_bounds__(256) void rgat_scan3(
    int* __restrict__ offs, const int* __restrict__ bsum) {
  const int base = blockIdx.x * 1024 + threadIdx.x * 4;
  const int b = bsum[blockIdx.x];
#pragma unroll
  for (int j = 0; j < 4; ++j)
    if (base + j < N3) offs[base + j] += b;
}

// scatter: czoff[pos] = r*RN+src (direct zb row id), cee[pos] = exp numerators
__global__ __launch_bounds__(256) void rgat_scatter(
    const int* __restrict__ src, const int* __restrict__ dst,
    const float* __restrict__ el, const float* __restrict__ er,
    int* __restrict__ offs2, int* __restrict__ czoff,
    float4* __restrict__ cee) {
  const int i = blockIdx.x * 256 + threadIdx.x;
  if (i >= NE3) return;
  const int r = i / RE;
  const int s = src[i];
  const int d = dst[i];
  const int pos = atomicAdd(&offs2[d * RR + r], 1);
  const float4 elv = *(const float4*)(el + (size_t)(r * (size_t)RN + s) * RH);
  const float4 erv = *(const float4*)(er + (size_t)(r * (size_t)RN + d) * RH);
  float e0 = elv.x + erv.x, e1 = elv.y + erv.y, e2 = elv.z + erv.z, e3 = elv.w + erv.w;
  e0 = e0 > 0.f ? e0 : 0.2f * e0;
  e1 = e1 > 0.f ? e1 : 0.2f * e1;
  e2 = e2 > 0.f ? e2 : 0.2f * e2;
  e3 = e3 > 0.f ? e3 : 0.2f * e3;
  czoff[pos] = r * RN + s;
  cee[pos] = make_float4(__expf(e0), __expf(e1), __expf(e2), __expf(e3));
}

// norm: one thread per (node,rel) key; normalize cee -> alpha IN PLACE
__global__ __launch_bounds__(256) void rgat_norm(
    float4* __restrict__ cee, const int* __restrict__ deg2,
    const int* __restrict__ offs2) {
  const int key = blockIdx.x * 256 + threadIdx.x;
  if (key >= N3) return;
  const int d = deg2[key];
  const int end = offs2[key];        // segment END after scatter
  float s0 = 0.f, s1 = 0.f, s2 = 0.f, s3 = 0.f;
  for (int p = end - d; p < end; ++p) {
    const float4 v = cee[p];
    s0 += v.x; s1 += v.y; s2 += v.z; s3 += v.w;
  }
  const float i0 = s0 > 0.f ? 1.f / s0 : 0.f;
  const float i1 = s1 > 0.f ? 1.f / s1 : 0.f;
  const float i2 = s2 > 0.f ? 1.f / s2 : 0.f;
  const float i3 = s3 > 0.f ? 1.f / s3 : 0.f;
  for (int p = end - d; p < end; ++p) {
    float4 v = cee[p];
    v.x *= i0; v.y *= i1; v.z *= i2; v.w *= i3;
    cee[p] = v;
  }
}

// -------- aggregate: block per node; half-wave per edge over MERGED segment --
__global__ __launch_bounds__(256) void rgat_aggregate(
    const unsigned short* __restrict__ zb, const int* __restrict__ czoff,
    const float* __restrict__ alpha, const int* __restrict__ deg2,
    const int* __restrict__ offs2, const float* __restrict__ bias,
    float* __restrict__ out) {
  __shared__ float shn[4][RHF];   // 4 KB
  const int n = blockIdx.x;
  const int tid = threadIdx.x;
  const int wid = tid >> 6, lane = tid & 63;
  const int hw = lane >> 5;
  const int sub = lane & 31;
  const int hwid = wid * 2 + hw;      // half-wave id 0..7
  const int h = sub >> 3;             // head of my 8 columns
  const int c = sub * 8;              // my 8 columns

  // merged segment: keys 3n..3n+2 are contiguous in the CSR
  const int k0 = n * RR;
  const int start = offs2[k0] - deg2[k0];
  const int dm = offs2[k0 + 2] - start;

  float acc[8] = {};
  const unsigned short* zB = zb + c;

  for (int base = 0; base < dm; base += 16) {
    int ss[2]; float aa[2];
#pragma unroll
    for (int j = 0; j < 2; ++j) {
      const int t = base + j * 8 + hwid;
      const int tc = t < dm ? t : dm - 1;     // clamped (dm>=1 inside loop)
      const int p = start + tc;
      ss[j] = czoff[p];
      const float af = alpha[p * 4 + h];
      aa[j] = t < dm ? af : 0.f;
    }
    short8 zv[2];
#pragma unroll
    for (int j = 0; j < 2; ++j)
      zv[j] = *(const short8*)(zB + (size_t)ss[j] * RHF);
#pragma unroll
    for (int j = 0; j < 2; ++j) {
      const float a = aa[j];
#pragma unroll
      for (int k = 0; k < 8; ++k)
        acc[k] += a * b2f((unsigned short)zv[j][k]);
    }
  }

  // fold the two half-waves
#pragma unroll
  for (int k = 0; k < 8; ++k) acc[k] += __shfl_xor(acc[k], 32);

  if (lane < 32) {
    *(float4*)&shn[wid][c]     = make_float4(acc[0], acc[1], acc[2], acc[3]);
    *(float4*)&shn[wid][c + 4] = make_float4(acc[4], acc[5], acc[6], acc[7]);
  }
  __syncthreads();

  const int col = tid;
  float v = shn[0][col] + shn[1][col] + shn[2][col] + shn[3][col]
          + bias[col] + bias[RHF + col] + bias[2 * RHF + col];
  v = v > 0.f ? v : (__expf(v) - 1.f);
  out[(size_t)n * RHF + col] = v;
}

extern "C" void kernel_launch(void* const* d_in, const int* in_sizes, int n_in,
                              void* d_out, int out_size, void* d_ws, size_t ws_size,
                              hipStream_t stream) {
  const float* x    = (const float*)d_in[0];
  const float* W    = (const float*)d_in[1];
  const float* al   = (const float*)d_in[2];
  const float* ar   = (const float*)d_in[3];
  const float* bias = (const float*)d_in[4];
  const int*   src  = (const int*)d_in[5];
  const int*   dst  = (const int*)d_in[6];
  float* out = (float*)d_out;

  // workspace layout (bytes), total ~248 MB
  char* p = (char*)d_ws;
  unsigned short* xb  = (unsigned short*)p; p += (size_t)RN * RIN * 2;        // 51.2 MB
  unsigned short* wbt = (unsigned short*)p; p += (size_t)RR * RIN * RHF * 2;  // 0.39 MB
  unsigned short* zb  = (unsigned short*)p; p += (size_t)RR * RN * RHF * 2;   // 153.6 MB
  float* el    = (float*)p;  p += (size_t)RR * RN * RH * 4;                   // 4.8 MB
  float* er    = (float*)p;  p += (size_t)RR * RN * RH * 4;                   // 4.8 MB
  int* deg2    = (int*)p;    p += (size_t)N3 * 4;                             // 1.2 MB
  int* offs2   = (int*)p;    p += (size_t)N3 * 4;                             // 1.2 MB
  int* czoff   = (int*)p;    p += (size_t)NE3 * 4;                            // 6.0 MB
  float4* cee  = (float4*)p; p += (size_t)NE3 * 16;                           // 24.0 MB
  int* bsum    = (int*)p;    p += 2048;

  const int NB1 = (N3 + 1023) / 1024;   // 293

  hipMemsetAsync(deg2, 0, (size_t)N3 * 4, stream);

  rgat_convx<<<(RN * RIN / 4 + 255) / 256, 256, 0, stream>>>(x, xb);
  rgat_convw<<<(RR * RIN * RHF + 255) / 256, 256, 0, stream>>>(W, wbt);

  rgat_hist<<<(NE3 + 255) / 256, 256, 0, stream>>>(dst, deg2);
  rgat_scan1<<<NB1, 256, 0, stream>>>(deg2, offs2, bsum);
  rgat_scan2<<<1, 512, 0, stream>>>(bsum, NB1);
  rgat_scan3<<<NB1, 256, 0, stream>>>(offs2, bsum);

  rgat_gemm_bf16<<<dim3((RN + 127) / 128, RHF / 128, RR), 256, 0, stream>>>(
      xb, wbt, zb, al, ar, el, er);

  rgat_scatter<<<(NE3 + 255) / 256, 256, 0, stream>>>(src, dst, el, er, offs2,
                                                      czoff, cee);

  rgat_norm<<<(N3 + 255) / 256, 256, 0, stream>>>(cee, deg2, offs2);

  rgat_aggregate<<<RN, 256, 0, stream>>>(zb, czoff, (const float*)cee, deg2,
                                         offs2, bias, out);
}

// Round 10
// 603.468 us; speedup vs baseline: 1.5983x; 1.0260x over previous
//
#include <hip/hip_runtime.h>
#include <hip/hip_bf16.h>

// RGAT encoder, round 10:
//  - GEMM with SWAPPED MFMA operands (A=W channels, B=x nodes): C rows=channels,
//    cols=nodes -> per-lane 4-consecutive-channel runs. Epilogue uses
//    v_cvt_pk_bf16_f32 + 8B dwordx2 z-stores (16 stores/lane vs 64 short-stores)
//    and el/er reduce with 2 shuffles (vs 8) per output. el/er stored f16.
//  - cee stored as f16x4 (8B/edge): halves scatter's scattered writes and
//    norm's traffic.
//  - aggregate: r9 structure unchanged (merged segment, half-wave per edge,
//    stride-1 distribution); alpha read as f16.

#define RN 100000
#define RE 500000
#define RH 4
#define RIN 256
#define RR 3
#define RHF 256
#define NE3 (RR * RE)
#define N3  (RR * RN)

typedef __attribute__((ext_vector_type(8))) short short8;
typedef __attribute__((ext_vector_type(4))) float f32x4;

static __device__ __forceinline__ float b2f(unsigned short u) {
  return __uint_as_float(((unsigned int)u) << 16);
}
static __device__ __forceinline__ unsigned short f2b(float f) {
  unsigned int u = __float_as_uint(f);
  u += 0x7FFF + ((u >> 16) & 1);   // RNE
  return (unsigned short)(u >> 16);
}
static __device__ __forceinline__ float h2f(unsigned short u) {
  return (float)__builtin_bit_cast(_Float16, u);
}
static __device__ __forceinline__ unsigned short f2h(float f) {
  return __builtin_bit_cast(unsigned short, (_Float16)f);
}
static __device__ __forceinline__ unsigned int cvt_pk_bf16(float lo, float hi) {
  unsigned int r;
  asm("v_cvt_pk_bf16_f32 %0, %1, %2" : "=v"(r) : "v"(lo), "v"(hi));
  return r;
}

// ---------------- conversions ----------------
__global__ __launch_bounds__(256) void rgat_convx(
    const float* __restrict__ x, unsigned short* __restrict__ xb) {
  const size_t i = ((size_t)blockIdx.x * 256 + threadIdx.x) * 4;
  if (i >= (size_t)RN * RIN) return;
  const float4 v = *(const float4*)(x + i);
  ushort4 o;
  o.x = f2b(v.x); o.y = f2b(v.y); o.z = f2b(v.z); o.w = f2b(v.w);
  *(ushort4*)(xb + i) = o;
}

// W[r][k][n] f32 -> Wbt[r][n][k] bf16
__global__ __launch_bounds__(256) void rgat_convw(
    const float* __restrict__ W, unsigned short* __restrict__ wbt) {
  const int o = blockIdx.x * 256 + threadIdx.x;
  if (o >= RR * RIN * RHF) return;
  const int r = o / (RIN * RHF);
  const int rem = o - r * (RIN * RHF);
  const int n = rem >> 8;
  const int k = rem & 255;
  wbt[o] = f2b(W[r * (RIN * RHF) + k * RHF + n]);
}

// ---- GEMM (swapped operands): C[ch, node]; packed bf16 z-store; f16 el/er ---
__global__ __launch_bounds__(256) void rgat_gemm_bf16(
    const unsigned short* __restrict__ xb, const unsigned short* __restrict__ wbt,
    unsigned short* __restrict__ zb, const float* __restrict__ al,
    const float* __restrict__ ar, unsigned short* __restrict__ elh,
    unsigned short* __restrict__ erh) {
  __shared__ unsigned short As[128 * 32];   // x node rows
  __shared__ unsigned short Bs[128 * 32];   // W channel rows (Wbt)
  const int tid = threadIdx.x;
  const int lane = tid & 63, wid = tid >> 6;
  const int wr = wid >> 1, wc = wid & 1;    // wr: channel half, wc: node half
  const int m0 = blockIdx.x * 128;          // node tile
  const int n0 = blockIdx.y * 128;          // channel tile
  const int r  = blockIdx.z;

  f32x4 acc[4][4] = {};   // [ci][xi]
  const unsigned short* Bbase = wbt + (size_t)r * (RIN * RHF);

  for (int k0 = 0; k0 < RIN; k0 += 32) {
#pragma unroll
    for (int i = 0; i < 2; ++i) {
      const int c = wid * 128 + i * 64 + lane;
      const int row = c >> 2, c4 = c & 3;
      const unsigned short* ga = xb + (size_t)(m0 + row) * RIN + k0 + c4 * 8;
      __builtin_amdgcn_global_load_lds(
          (const __attribute__((address_space(1))) void*)ga,
          (__attribute__((address_space(3))) void*)(As + (wid * 128 + i * 64) * 8),
          16, 0, 0);
      const unsigned short* gb = Bbase + (size_t)(n0 + row) * RIN + k0 + c4 * 8;
      __builtin_amdgcn_global_load_lds(
          (const __attribute__((address_space(1))) void*)gb,
          (__attribute__((address_space(3))) void*)(Bs + (wid * 128 + i * 64) * 8),
          16, 0, 0);
    }
    asm volatile("s_waitcnt vmcnt(0)" ::: "memory");
    __syncthreads();

    short8 wf[4], xf[4];
#pragma unroll
    for (int ci = 0; ci < 4; ++ci)
      wf[ci] = *(const short8*)(Bs + ((wr * 64 + ci * 16 + (lane & 15)) * 32 + (lane >> 4) * 8));
#pragma unroll
    for (int xi = 0; xi < 4; ++xi)
      xf[xi] = *(const short8*)(As + ((wc * 64 + xi * 16 + (lane & 15)) * 32 + (lane >> 4) * 8));
#pragma unroll
    for (int ci = 0; ci < 4; ++ci)
#pragma unroll
      for (int xi = 0; xi < 4; ++xi)
        acc[ci][xi] = __builtin_amdgcn_mfma_f32_16x16x32_bf16(wf[ci], xf[xi], acc[ci][xi], 0, 0, 0);
    __syncthreads();
  }

  // epilogue: lane holds, per xi, one node and 16 channels (4 runs of 4).
  const int head = blockIdx.y * 2 + wr;     // this wave's head
  const int g4 = (lane >> 4) * 4;
  float alv[4][4], arv[4][4];
#pragma unroll
  for (int ci = 0; ci < 4; ++ci) {
    const float4 a4 = *(const float4*)(al + r * RHF + head * 64 + ci * 16 + g4);
    const float4 b4 = *(const float4*)(ar + r * RHF + head * 64 + ci * 16 + g4);
    alv[ci][0] = a4.x; alv[ci][1] = a4.y; alv[ci][2] = a4.z; alv[ci][3] = a4.w;
    arv[ci][0] = b4.x; arv[ci][1] = b4.y; arv[ci][2] = b4.z; arv[ci][3] = b4.w;
  }

#pragma unroll
  for (int xi = 0; xi < 4; ++xi) {
    const int node = m0 + wc * 64 + xi * 16 + (lane & 15);
    unsigned short* zrow = zb + (size_t)r * ((size_t)RN * RHF) + (size_t)node * RHF
                           + n0 + wr * 64 + g4;
    float pl = 0.f, pr = 0.f;
#pragma unroll
    for (int ci = 0; ci < 4; ++ci) {
      const f32x4 a = acc[ci][xi];
      uint2 pk;
      pk.x = cvt_pk_bf16(a[0], a[1]);
      pk.y = cvt_pk_bf16(a[2], a[3]);
      if (node < RN) *(uint2*)(zrow + ci * 16) = pk;
      pl += a[0] * alv[ci][0] + a[1] * alv[ci][1] + a[2] * alv[ci][2] + a[3] * alv[ci][3];
      pr += a[0] * arv[ci][0] + a[1] * arv[ci][1] + a[2] * arv[ci][2] + a[3] * arv[ci][3];
    }
    pl += __shfl_xor(pl, 16); pl += __shfl_xor(pl, 32);
    pr += __shfl_xor(pr, 16); pr += __shfl_xor(pr, 32);
    if (lane < 16 && node < RN) {
      const size_t key = (size_t)r * RN + node;
      elh[key * RH + head] = f2h(pl);
      erh[key * RH + head] = f2h(pr);
    }
  }
}

// ---------------- CSR build keyed by (node, relation) ----------------
__global__ __launch_bounds__(256) void rgat_hist(
    const int* __restrict__ dst, int* __restrict__ deg2) {
  const int i = blockIdx.x * 256 + threadIdx.x;
  if (i >= NE3) return;
  const int r = i / RE;
  atomicAdd(&deg2[dst[i] * RR + r], 1);
}

__global__ __launch_bounds__(256) void rgat_scan1(
    const int* __restrict__ deg, int* __restrict__ offs, int* __restrict__ bsum) {
  __shared__ int sh[256];
  const int tid = threadIdx.x;
  const int base = blockIdx.x * 1024 + tid * 4;
  int v[4]; int s = 0;
#pragma unroll
  for (int j = 0; j < 4; ++j) {
    v[j] = (base + j < N3) ? deg[base + j] : 0;
    s += v[j];
  }
  sh[tid] = s;
  __syncthreads();
  for (int off = 1; off < 256; off <<= 1) {
    int t = (tid >= off) ? sh[tid - off] : 0;
    __syncthreads();
    sh[tid] += t;
    __syncthreads();
  }
  int run = sh[tid] - s;
  if (tid == 255) bsum[blockIdx.x] = sh[255];
#pragma unroll
  for (int j = 0; j < 4; ++j) {
    if (base + j < N3) offs[base + j] = run;
    run += v[j];
  }
}

__global__ __launch_bounds__(512) void rgat_scan2(int* __restrict__ bsum, int nb) {
  __shared__ int sh[512];
  const int tid = threadIdx.x;
  const int v = (tid < nb) ? bsum[tid] : 0;
  sh[tid] = v;
  __syncthreads();
  for (int off = 1; off < 512; off <<= 1) {
    int t = (tid >= off) ? sh[tid - off] : 0;
    __syncthreads();
    sh[tid] += t;
    __syncthreads();
  }
  if (tid < nb) bsum[tid] = sh[tid] - v;
}

__global__ __launch_bounds__(256) void rgat_scan3(
    int* __restrict__ offs, const int* __restrict__ bsum) {
  const int base = blockIdx.x * 1024 + threadIdx.x * 4;
  const int b = bsum[blockIdx.x];
#pragma unroll
  for (int j = 0; j < 4; ++j)
    if (base + j < N3) offs[base + j] += b;
}

// scatter: czoff[pos] = r*RN+src, cee[pos] = f16x4 exp numerators
__global__ __launch_bounds__(256) void rgat_scatter(
    const int* __restrict__ src, const int* __restrict__ dst,
    const unsigned short* __restrict__ elh, const unsigned short* __restrict__ erh,
    int* __restrict__ offs2, int* __restrict__ czoff,
    unsigned short* __restrict__ ceeh) {
  const int i = blockIdx.x * 256 + threadIdx.x;
  if (i >= NE3) return;
  const int r = i / RE;
  const int s = src[i];
  const int d = dst[i];
  const int pos = atomicAdd(&offs2[d * RR + r], 1);
  const uint2 eu = *(const uint2*)(elh + ((size_t)r * RN + s) * RH);
  const uint2 ru = *(const uint2*)(erh + ((size_t)r * RN + d) * RH);
  float e0 = h2f((unsigned short)eu.x) + h2f((unsigned short)ru.x);
  float e1 = h2f((unsigned short)(eu.x >> 16)) + h2f((unsigned short)(ru.x >> 16));
  float e2 = h2f((unsigned short)eu.y) + h2f((unsigned short)ru.y);
  float e3 = h2f((unsigned short)(eu.y >> 16)) + h2f((unsigned short)(ru.y >> 16));
  e0 = e0 > 0.f ? e0 : 0.2f * e0;
  e1 = e1 > 0.f ? e1 : 0.2f * e1;
  e2 = e2 > 0.f ? e2 : 0.2f * e2;
  e3 = e3 > 0.f ? e3 : 0.2f * e3;
  czoff[pos] = r * RN + s;
  uint2 o;
  o.x = (unsigned int)f2h(__expf(e0)) | ((unsigned int)f2h(__expf(e1)) << 16);
  o.y = (unsigned int)f2h(__expf(e2)) | ((unsigned int)f2h(__expf(e3)) << 16);
  *(uint2*)(ceeh + (size_t)pos * 4) = o;
}

// norm: one thread per (node,rel) key; normalize cee -> alpha IN PLACE (f16)
__global__ __launch_bounds__(256) void rgat_norm(
    unsigned short* __restrict__ ceeh, const int* __restrict__ deg2,
    const int* __restrict__ offs2) {
  const int key = blockIdx.x * 256 + threadIdx.x;
  if (key >= N3) return;
  const int d = deg2[key];
  const int end = offs2[key];
  float s0 = 0.f, s1 = 0.f, s2 = 0.f, s3 = 0.f;
  for (int p = end - d; p < end; ++p) {
    const uint2 v = *(const uint2*)(ceeh + (size_t)p * 4);
    s0 += h2f((unsigned short)v.x);
    s1 += h2f((unsigned short)(v.x >> 16));
    s2 += h2f((unsigned short)v.y);
    s3 += h2f((unsigned short)(v.y >> 16));
  }
  const float i0 = s0 > 0.f ? 1.f / s0 : 0.f;
  const float i1 = s1 > 0.f ? 1.f / s1 : 0.f;
  const float i2 = s2 > 0.f ? 1.f / s2 : 0.f;
  const float i3 = s3 > 0.f ? 1.f / s3 : 0.f;
  for (int p = end - d; p < end; ++p) {
    uint2 v = *(const uint2*)(ceeh + (size_t)p * 4);
    const float a0 = h2f((unsigned short)v.x) * i0;
    const float a1 = h2f((unsigned short)(v.x >> 16)) * i1;
    const float a2 = h2f((unsigned short)v.y) * i2;
    const float a3 = h2f((unsigned short)(v.y >> 16)) * i3;
    v.x = (unsigned int)f2h(a0) | ((unsigned int)f2h(a1) << 16);
    v.y = (unsigned int)f2h(a2) | ((unsigned int)f2h(a3) << 16);
    *(uint2*)(ceeh + (size_t)p * 4) = v;
  }
}

// -------- aggregate: block per node; half-wave per edge over MERGED segment --
__global__ __launch_bounds__(256) void rgat_aggregate(
    const unsigned short* __restrict__ zb, const int* __restrict__ czoff,
    const unsigned short* __restrict__ ceeh, const int* __restrict__ deg2,
    const int* __restrict__ offs2, const float* __restrict__ bias,
    float* __restrict__ out) {
  __shared__ float shn[4][RHF];   // 4 KB
  const int n = blockIdx.x;
  const int tid = threadIdx.x;
  const int wid = tid >> 6, lane = tid & 63;
  const int hw = lane >> 5;
  const int sub = lane & 31;
  const int hwid = wid * 2 + hw;      // half-wave id 0..7
  const int h = sub >> 3;             // head of my 8 columns
  const int c = sub * 8;              // my 8 columns

  const int k0 = n * RR;
  const int start = offs2[k0] - deg2[k0];
  const int dm = offs2[k0 + 2] - start;

  float acc[8] = {};
  const unsigned short* zB = zb + c;

  for (int base = 0; base < dm; base += 16) {
    int ss[2]; float aa[2];
#pragma unroll
    for (int j = 0; j < 2; ++j) {
      const int t = base + j * 8 + hwid;
      const int tc = t < dm ? t : dm - 1;
      const int p = start + tc;
      ss[j] = czoff[p];
      const float af = h2f(ceeh[(size_t)p * 4 + h]);
      aa[j] = t < dm ? af : 0.f;
    }
    short8 zv[2];
#pragma unroll
    for (int j = 0; j < 2; ++j)
      zv[j] = *(const short8*)(zB + (size_t)ss[j] * RHF);
#pragma unroll
    for (int j = 0; j < 2; ++j) {
      const float a = aa[j];
#pragma unroll
      for (int k = 0; k < 8; ++k)
        acc[k] += a * b2f((unsigned short)zv[j][k]);
    }
  }

#pragma unroll
  for (int k = 0; k < 8; ++k) acc[k] += __shfl_xor(acc[k], 32);

  if (lane < 32) {
    *(float4*)&shn[wid][c]     = make_float4(acc[0], acc[1], acc[2], acc[3]);
    *(float4*)&shn[wid][c + 4] = make_float4(acc[4], acc[5], acc[6], acc[7]);
  }
  __syncthreads();

  const int col = tid;
  float v = shn[0][col] + shn[1][col] + shn[2][col] + shn[3][col]
          + bias[col] + bias[RHF + col] + bias[2 * RHF + col];
  v = v > 0.f ? v : (__expf(v) - 1.f);
  out[(size_t)n * RHF + col] = v;
}

extern "C" void kernel_launch(void* const* d_in, const int* in_sizes, int n_in,
                              void* d_out, int out_size, void* d_ws, size_t ws_size,
                              hipStream_t stream) {
  const float* x    = (const float*)d_in[0];
  const float* W    = (const float*)d_in[1];
  const float* al   = (const float*)d_in[2];
  const float* ar   = (const float*)d_in[3];
  const float* bias = (const float*)d_in[4];
  const int*   src  = (const int*)d_in[5];
  const int*   dst  = (const int*)d_in[6];
  float* out = (float*)d_out;

  // workspace layout (bytes), total ~232 MB
  char* p = (char*)d_ws;
  unsigned short* xb   = (unsigned short*)p; p += (size_t)RN * RIN * 2;        // 51.2 MB
  unsigned short* wbt  = (unsigned short*)p; p += (size_t)RR * RIN * RHF * 2;  // 0.39 MB
  unsigned short* zb   = (unsigned short*)p; p += (size_t)RR * RN * RHF * 2;   // 153.6 MB
  unsigned short* elh  = (unsigned short*)p; p += (size_t)N3 * RH * 2;         // 2.4 MB
  unsigned short* erh  = (unsigned short*)p; p += (size_t)N3 * RH * 2;         // 2.4 MB
  int* deg2    = (int*)p;    p += (size_t)N3 * 4;                              // 1.2 MB
  int* offs2   = (int*)p;    p += (size_t)N3 * 4;                              // 1.2 MB
  int* czoff   = (int*)p;    p += (size_t)NE3 * 4;                             // 6.0 MB
  unsigned short* ceeh = (unsigned short*)p; p += (size_t)NE3 * RH * 2;        // 12.0 MB
  int* bsum    = (int*)p;    p += 2048;

  const int NB1 = (N3 + 1023) / 1024;   // 293

  hipMemsetAsync(deg2, 0, (size_t)N3 * 4, stream);

  rgat_convx<<<(RN * RIN / 4 + 255) / 256, 256, 0, stream>>>(x, xb);
  rgat_convw<<<(RR * RIN * RHF + 255) / 256, 256, 0, stream>>>(W, wbt);

  rgat_hist<<<(NE3 + 255) / 256, 256, 0, stream>>>(dst, deg2);
  rgat_scan1<<<NB1, 256, 0, stream>>>(deg2, offs2, bsum);
  rgat_scan2<<<1, 512, 0, stream>>>(bsum, NB1);
  rgat_scan3<<<NB1, 256, 0, stream>>>(offs2, bsum);

  rgat_gemm_bf16<<<dim3((RN + 127) / 128, RHF / 128, RR), 256, 0, stream>>>(
      xb, wbt, zb, al, ar, elh, erh);

  rgat_scatter<<<(NE3 + 255) / 256, 256, 0, stream>>>(src, dst, elh, erh, offs2,
                                                      czoff, ceeh);

  rgat_norm<<<(N3 + 255) / 256, 256, 0, stream>>>(ceeh, deg2, offs2);

  rgat_aggregate<<<RN, 256, 0, stream>>>(zb, czoff, ceeh, deg2, offs2, bias, out);
}